// Round 3
// baseline (295.250 us; speedup 1.0000x reference)
//
#include <hip/hip_runtime.h>
#include <hip/hip_bf16.h>

// ---------- types ----------
typedef short s8v  __attribute__((ext_vector_type(8)));   // 8 x bf16 (4 VGPRs)
typedef float f16v __attribute__((ext_vector_type(16)));  // 32x32 accumulator

#define NUM_EMBEDS 8192
#define EMBED_DIM  256
#define BATCH      16
#define HW         1024
#define NVEC       (BATCH * HW)              // 16384
#define OUT0_ELEMS (BATCH * EMBED_DIM * HW)  // 4194304

// LDS map (dynamic, 160 KiB):
//   buf0 @ 0      (64 KiB)  B tile, K-major [ks][hi][128 cols][16B]
//   buf1 @ 65536  (64 KiB)  (also holds A stage during prologue)
//   e2   @ 131072 (32 KiB)  all 8192 ||e||^2 floats
#define BUFSZ  65536
#define E2OFF  131072
#define SMEMSZ 163840

static __device__ __forceinline__ unsigned short f32_to_bf16_rne(float f) {
    unsigned int u = __float_as_uint(f);
    unsigned int r = u + 0x7FFFu + ((u >> 16) & 1u);
    return (unsigned short)(r >> 16);
}

static __device__ __forceinline__ void gload_lds16(const void* g, void* l) {
    __builtin_amdgcn_global_load_lds(
        (const __attribute__((address_space(1))) unsigned int*)g,
        (__attribute__((address_space(3))) unsigned int*)l, 16, 0, 0);
}
static __device__ __forceinline__ void gload_lds4(const void* g, void* l) {
    __builtin_amdgcn_global_load_lds(
        (const __attribute__((address_space(1))) unsigned int*)g,
        (__attribute__((address_space(3))) unsigned int*)l, 4, 0, 0);
}

// ---------- kernel 1: transpose x [16][256][1024] f32 -> xb [16384][256] bf16 ----------
__global__ void k_transpose_x(const float* __restrict__ x, unsigned short* __restrict__ xb,
                              float* __restrict__ loss) {
    __shared__ float t[32][33];
    const int tx = threadIdx.x;          // 0..31
    const int ty = threadIdx.y;          // 0..7
    const int hw0 = blockIdx.x * 32;
    const int c0  = blockIdx.y * 32;
    const int b   = blockIdx.z;
    if (blockIdx.x == 0 && blockIdx.y == 0 && blockIdx.z == 0 && tx == 0 && ty == 0)
        *loss = 0.0f;
    #pragma unroll
    for (int i = 0; i < 4; ++i) {
        const int c = c0 + ty + i * 8;
        t[ty + i * 8][tx] = x[((b * EMBED_DIM + c) << 10) + hw0 + tx];
    }
    __syncthreads();
    #pragma unroll
    for (int i = 0; i < 4; ++i) {
        const int hw = hw0 + ty + i * 8;
        const int n = b * HW + hw;
        xb[n * EMBED_DIM + c0 + tx] = f32_to_bf16_rne(t[tx][ty + i * 8]);
    }
}

// ---------- kernel 2: codebook f32 -> bf16 + e2 ----------
__global__ void k_convert_cb(const float* __restrict__ cb, unsigned short* __restrict__ eb,
                             float* __restrict__ e2) {
    const int e = blockIdx.x;
    const int tid = threadIdx.x;      // 0..255
    const float v = cb[e * EMBED_DIM + tid];
    eb[e * EMBED_DIM + tid] = f32_to_bf16_rne(v);
    float s = v * v;
    #pragma unroll
    for (int off = 32; off > 0; off >>= 1) s += __shfl_down(s, off, 64);
    __shared__ float ls[4];
    const int lane = tid & 63, wid = tid >> 6;
    if (lane == 0) ls[wid] = s;
    __syncthreads();
    if (tid == 0) e2[e] = ls[0] + ls[1] + ls[2] + ls[3];
}

// ---------- kernel 3: fused GEMM + argmin, A-in-regs, dbuf LDS B, counted vmcnt ----------
// 256 blocks x 256 thr (4 waves). Block = 64 rows; iter = 128 cols (32/wave); 64 iters.
__global__ void __launch_bounds__(256, 1)
k_argmin(const unsigned short* __restrict__ xb, const unsigned short* __restrict__ eb,
         const float* __restrict__ e2, int* __restrict__ idxout) {
    extern __shared__ char smem[];
    const int tid  = threadIdx.x;
    const int lane = tid & 63;
    const int w    = tid >> 6;           // wave 0..3
    const int l31  = lane & 31;
    const int hi   = lane >> 5;          // 0/1
    const int row0 = blockIdx.x * 64;

    const char* xbB = (const char*)xb;
    const char* ebB = (const char*)eb;
    const char* e2B = (const char*)e2;

    // ---- prologue staging ----
    // e2: 32 KiB = 32 x 1KiB instrs, 8 per wave
    #pragma unroll
    for (int j = 0; j < 8; ++j) {
        const int inst = w * 8 + j;
        gload_lds16(e2B + inst * 1024 + lane * 16, smem + E2OFF + inst * 1024);
    }
    // A: rows [row0, row0+64) K-major [ks][hi][64 rows][16B] into buf1; 32 instrs, 8/wave
    #pragma unroll
    for (int j = 0; j < 4; ++j) {
        const int ks = w * 4 + j;
        #pragma unroll
        for (int h = 0; h < 2; ++h) {
            gload_lds16(xbB + ((size_t)(row0 + lane) << 9) + ks * 32 + h * 16,
                        smem + BUFSZ + ((ks * 2 + h) * 64) * 16);
        }
    }
    // B tile 0 -> buf0: 16 instrs/wave
    {
        const int colbase = 0;
        #pragma unroll
        for (int j = 0; j < 4; ++j) {
            const int ks = w * 4 + j;
            #pragma unroll
            for (int h = 0; h < 2; ++h)
                #pragma unroll
                for (int ch = 0; ch < 2; ++ch) {
                    gload_lds16(ebB + ((size_t)(colbase + ch * 64 + lane) << 9) + ks * 32 + h * 16,
                                smem + (((ks * 2 + h) * 128) + ch * 64) * 16);
                }
        }
    }
    asm volatile("s_waitcnt vmcnt(16)" ::: "memory");  // e2 + A landed; tile0 may fly
    __builtin_amdgcn_s_barrier();
    asm volatile("" ::: "memory");

    // ---- A fragments into registers: afr[mr][ks], 128 VGPRs ----
    s8v afr[2][16];
    #pragma unroll
    for (int mr = 0; mr < 2; ++mr)
        #pragma unroll
        for (int ks = 0; ks < 16; ++ks)
            afr[mr][ks] = *reinterpret_cast<const s8v*>(
                smem + BUFSZ + (((ks * 2 + hi) * 64) + mr * 32 + l31) * 16);
    asm volatile("s_waitcnt lgkmcnt(0)" ::: "memory");

    float minv0[16], minv1[16];
    int   minc0[16], minc1[16];
    #pragma unroll
    for (int r = 0; r < 16; ++r) {
        minv0[r] = 3.4e38f; minv1[r] = 3.4e38f; minc0[r] = 0; minc1[r] = 0;
    }

    // ---- main loop over 64 col-tiles of 128 ----
    for (int t = 0; t < 64; ++t) {
        const int bufoff = (t & 1) * BUFSZ;
        __builtin_amdgcn_s_barrier();                 // B1: everyone done reading other buf
        asm volatile("" ::: "memory");
        if (t < 63) {
            const int colbase = (t + 1) * 128;
            const int nbuf = BUFSZ - bufoff;
            #pragma unroll
            for (int j = 0; j < 4; ++j) {
                const int ks = w * 4 + j;
                #pragma unroll
                for (int h = 0; h < 2; ++h)
                    #pragma unroll
                    for (int ch = 0; ch < 2; ++ch) {
                        gload_lds16(ebB + ((size_t)(colbase + ch * 64 + lane) << 9) + ks * 32 + h * 16,
                                    smem + nbuf + (((ks * 2 + h) * 128) + ch * 64) * 16);
                    }
            }
            asm volatile("s_waitcnt vmcnt(16)" ::: "memory");   // current tile fully landed
        } else {
            asm volatile("s_waitcnt vmcnt(0)" ::: "memory");
        }
        __builtin_amdgcn_s_barrier();                 // B2: all waves' parts landed
        asm volatile("" ::: "memory");

        const float ev = *reinterpret_cast<const float*>(
            smem + E2OFF + ((size_t)(t * 128 + w * 32 + l31) << 2));

        f16v a0{}, a1{};
        #pragma unroll
        for (int ks = 0; ks < 16; ++ks) {
            const s8v bf = *reinterpret_cast<const s8v*>(
                smem + bufoff + (((ks * 2 + hi) * 128) + w * 32 + l31) * 16);
            a0 = __builtin_amdgcn_mfma_f32_32x32x16_bf16(afr[0][ks], bf, a0, 0, 0, 0);
            a1 = __builtin_amdgcn_mfma_f32_32x32x16_bf16(afr[1][ks], bf, a1, 0, 0, 0);
        }

        const int cbw = t * 128 + w * 32;
        #pragma unroll
        for (int r = 0; r < 16; ++r) {
            const float s0 = fmaf(-2.0f, a0[r], ev);
            if (s0 < minv0[r]) { minv0[r] = s0; minc0[r] = cbw; }
            const float s1 = fmaf(-2.0f, a1[r], ev);
            if (s1 < minv1[r]) { minv1[r] = s1; minc1[r] = cbw; }
        }
        asm volatile("s_waitcnt lgkmcnt(0)" ::: "memory");  // reads done before next B1
    }

    // ---- final reduce: butterfly over 32 col-lanes, then cross-wave via LDS ----
    float* scrV = (float*)smem;              // buf0 region reused (safe post-loop)
    int*   scrC = (int*)(smem + 4096);
    #pragma unroll
    for (int mr = 0; mr < 2; ++mr)
        #pragma unroll
        for (int r = 0; r < 16; ++r) {
            float v = mr ? minv1[r] : minv0[r];
            int   c = (mr ? minc1[r] : minc0[r]) + l31;
            #pragma unroll
            for (int m = 1; m <= 16; m <<= 1) {
                const float v2 = __shfl_xor(v, m, 64);
                const int   c2 = __shfl_xor(c, m, 64);
                if (v2 < v || (v2 == v && c2 < c)) { v = v2; c = c2; }
            }
            if (l31 == 0) {
                const int row = mr * 32 + (r & 3) + 8 * (r >> 2) + 4 * hi;
                scrV[w * 64 + row] = v;
                scrC[w * 64 + row] = c;
            }
        }
    __syncthreads();
    if (tid < 64) {
        float v = scrV[tid]; int c = scrC[tid];
        #pragma unroll
        for (int ww = 1; ww < 4; ++ww) {
            const float v2 = scrV[ww * 64 + tid];
            const int   c2 = scrC[ww * 64 + tid];
            if (v2 < v || (v2 == v && c2 < c)) { v = v2; c = c2; }
        }
        idxout[row0 + tid] = c;
    }
}

// ---------- kernel 4: gather + straight-through output + loss partial ----------
__global__ void __launch_bounds__(256)
k_gather_loss(const float* __restrict__ x, const float* __restrict__ cb,
              const int* __restrict__ idx, float* __restrict__ out,
              float* __restrict__ loss) {
    __shared__ float q[32][257];
    __shared__ int e_s[32];
    const int tid = threadIdx.x;
    const int hw0 = (blockIdx.x & 31) * 32;
    const int b   = blockIdx.x >> 5;
    const int n0  = (b << 10) + hw0;
    if (tid < 32) e_s[tid] = idx[n0 + tid];
    __syncthreads();
    #pragma unroll 8
    for (int r = 0; r < 32; ++r)
        q[r][tid] = cb[(size_t)e_s[r] * EMBED_DIM + tid];
    __syncthreads();
    const int tx = tid & 31;    // hw offset within tile
    const int ty = tid >> 5;    // 0..7  (channel group)
    float sum = 0.f;
    #pragma unroll
    for (int i = 0; i < 32; ++i) {
        const int c = ty * 32 + i;
        const float qv = q[tx][c];
        const int o = ((b * EMBED_DIM + c) << 10) + hw0 + tx;
        const float xv = x[o];
        out[o] = qv;
        const float d = qv - xv;
        sum = fmaf(d, d, sum);
    }
    #pragma unroll
    for (int off = 32; off > 0; off >>= 1) sum += __shfl_down(sum, off, 64);
    __shared__ float ls[4];
    const int lane = tid & 63, wid = tid >> 6;
    if (lane == 0) ls[wid] = sum;
    __syncthreads();
    if (tid == 0) atomicAdd(loss, ls[0] + ls[1] + ls[2] + ls[3]);
}

// ---------- kernel 5: finalize loss ----------
__global__ void k_finalize(const float* __restrict__ loss, float* __restrict__ out) {
    out[OUT0_ELEMS] = loss[0] * (1.25f / (float)OUT0_ELEMS);
}

extern "C" void kernel_launch(void* const* d_in, const int* in_sizes, int n_in,
                              void* d_out, int out_size, void* d_ws, size_t ws_size,
                              hipStream_t stream) {
    const float* x  = (const float*)d_in[0];
    const float* cb = (const float*)d_in[1];
    float* out = (float*)d_out;

    char* ws = (char*)d_ws;
    unsigned short* xb = (unsigned short*)ws;                         // 8 MB
    unsigned short* eb = (unsigned short*)(ws + 8388608);             // 4 MB
    float* e2   = (float*)(ws + 12582912);                            // 32 KB
    int*   idx  = (int*)(ws + 12615680);                              // 64 KB
    float* loss = (float*)(ws + 12681216);                            // 4 B

    k_transpose_x<<<dim3(32, 8, 16), dim3(32, 8, 1), 0, stream>>>(x, xb, loss);
    k_convert_cb<<<dim3(NUM_EMBEDS), dim3(256), 0, stream>>>(cb, eb, e2);
    k_argmin<<<dim3(NVEC / 64), dim3(256), SMEMSZ, stream>>>(xb, eb, e2, idx);
    k_gather_loss<<<dim3(512), dim3(256), 0, stream>>>(x, cb, idx, out, loss);
    k_finalize<<<dim3(1), dim3(1), 0, stream>>>(loss, out);
}

// Round 4
// 142.911 us; speedup vs baseline: 2.0660x; 2.0660x over previous
//
#include <hip/hip_runtime.h>
#include <hip/hip_bf16.h>

// ---------- types ----------
typedef short s8v  __attribute__((ext_vector_type(8)));   // 8 x bf16 (4 VGPRs)
typedef float f16v __attribute__((ext_vector_type(16)));  // 32x32 accumulator

#define NUM_EMBEDS 8192
#define EMBED_DIM  256
#define BATCH      16
#define HW         1024
#define NVEC       (BATCH * HW)              // 16384
#define OUT0_ELEMS (BATCH * EMBED_DIM * HW)  // 4194304

// LDS map (dynamic, 160 KiB):
//   buf0 @ 0      (64 KiB)  B tile, row-major [128 cols][512B], XOR-swizzled chunks
//   buf1 @ 65536  (64 KiB)
//   e2   @ 131072 (32 KiB)  all 8192 ||e||^2 floats
#define BUFSZ  65536
#define E2OFF  131072
#define SMEMSZ 163840

static __device__ __forceinline__ unsigned short f32_to_bf16_rne(float f) {
    unsigned int u = __float_as_uint(f);
    unsigned int r = u + 0x7FFFu + ((u >> 16) & 1u);
    return (unsigned short)(r >> 16);
}

static __device__ __forceinline__ void gload_lds16(const void* g, void* l) {
    __builtin_amdgcn_global_load_lds(
        (const __attribute__((address_space(1))) unsigned int*)g,
        (__attribute__((address_space(3))) unsigned int*)l, 16, 0, 0);
}

// ---------- kernel 1: transpose x [16][256][1024] f32 -> xb [16384][256] bf16 ----------
__global__ void k_transpose_x(const float* __restrict__ x, unsigned short* __restrict__ xb,
                              float* __restrict__ loss) {
    __shared__ float t[32][33];
    const int tx = threadIdx.x;          // 0..31
    const int ty = threadIdx.y;          // 0..7
    const int hw0 = blockIdx.x * 32;
    const int c0  = blockIdx.y * 32;
    const int b   = blockIdx.z;
    if (blockIdx.x == 0 && blockIdx.y == 0 && blockIdx.z == 0 && tx == 0 && ty == 0)
        *loss = 0.0f;
    #pragma unroll
    for (int i = 0; i < 4; ++i) {
        const int c = c0 + ty + i * 8;
        t[ty + i * 8][tx] = x[((b * EMBED_DIM + c) << 10) + hw0 + tx];
    }
    __syncthreads();
    #pragma unroll
    for (int i = 0; i < 4; ++i) {
        const int hw = hw0 + ty + i * 8;
        const int n = b * HW + hw;
        xb[n * EMBED_DIM + c0 + tx] = f32_to_bf16_rne(t[tx][ty + i * 8]);
    }
}

// ---------- kernel 2: codebook f32 -> bf16 + e2 ----------
__global__ void k_convert_cb(const float* __restrict__ cb, unsigned short* __restrict__ eb,
                             float* __restrict__ e2) {
    const int e = blockIdx.x;
    const int tid = threadIdx.x;      // 0..255
    const float v = cb[e * EMBED_DIM + tid];
    eb[e * EMBED_DIM + tid] = f32_to_bf16_rne(v);
    float s = v * v;
    #pragma unroll
    for (int off = 32; off > 0; off >>= 1) s += __shfl_down(s, off, 64);
    __shared__ float ls[4];
    const int lane = tid & 63, wid = tid >> 6;
    if (lane == 0) ls[wid] = s;
    __syncthreads();
    if (tid == 0) e2[e] = ls[0] + ls[1] + ls[2] + ls[3];
}

// ---------- kernel 3: fused GEMM + argmin ----------
// 256 blocks x 256 thr (4 waves), 1 block/CU. Block = 64 rows; tile = 128 cols; 64 tiles.
// A (64x256 bf16) lives in registers (128 VGPR, pinned). B staged coalesced+swizzled.
__global__ void __launch_bounds__(256, 1)
k_argmin(const unsigned short* __restrict__ xb, const unsigned short* __restrict__ eb,
         const float* __restrict__ e2, int* __restrict__ idxout) {
    extern __shared__ char smem[];
    const int tid  = threadIdx.x;
    const int lane = tid & 63;
    const int w    = tid >> 6;           // wave 0..3
    const int l31  = lane & 31;
    const int hi   = lane >> 5;          // 0/1
    const int row0 = blockIdx.x * 64;

    const char* xbB = (const char*)xb;
    const char* ebB = (const char*)eb;
    const char* e2B = (const char*)e2;

    // ---- A fragments straight from global (one-time scatter; 32 x 16B per lane) ----
    // 32x32x16 A layout: lane: row = l31 (+ mr*32), k = ks*16 + hi*8 + j
    s8v afr[2][16];
    #pragma unroll
    for (int mr = 0; mr < 2; ++mr)
        #pragma unroll
        for (int ks = 0; ks < 16; ++ks)
            afr[mr][ks] = *reinterpret_cast<const s8v*>(
                xbB + ((size_t)(row0 + mr * 32 + l31) << 9) + ks * 32 + hi * 16);

    // ---- e2 stage: 32 KiB, 8 instrs/wave, linear ----
    #pragma unroll
    for (int j = 0; j < 8; ++j) {
        const int inst = w * 8 + j;
        gload_lds16(e2B + inst * 1024 + lane * 16, smem + E2OFF + inst * 1024);
    }

    // ---- B staging: row-major [128][512B], chunk-XOR swizzle; coalesced source ----
    // instr (w,j): rows 2p,2p+1 (p=w*16+j), contiguous 1KB. Lane l -> row r=2p+hi,
    // chunk i=l31. LDS[r*512 + i*16] gets global byte ((i ^ (r&7))*16) of row.
    auto STAGE = [&](int colbase, int lds_off) {
        #pragma unroll
        for (int j = 0; j < 16; ++j) {
            const int p = w * 16 + j;
            const int r = 2 * p + hi;
            gload_lds16(ebB + ((size_t)(colbase + r) << 9) + ((l31 ^ (r & 7)) << 4),
                        smem + lds_off + p * 1024);
        }
    };
    STAGE(0, 0);

    // pin A in registers (opaque to the optimizer -> no sinking/rematerialization)
    #pragma unroll
    for (int mr = 0; mr < 2; ++mr)
        #pragma unroll
        for (int ks = 0; ks < 16; ++ks)
            asm volatile("" : "+v"(afr[mr][ks]));

    float minv0[16], minv1[16];
    int   minc0[16], minc1[16];
    #pragma unroll
    for (int r = 0; r < 16; ++r) {
        minv0[r] = 3.4e38f; minv1[r] = 3.4e38f; minc0[r] = 0; minc1[r] = 0;
    }

    const int rloc = w * 32 + l31;        // this lane's B col within the tile
    const int sx   = (rloc & 7) << 4;     // read-side swizzle
    const char* e2p = smem + E2OFF + ((size_t)rloc << 2);

    for (int t = 0; t < 64; ++t) {
        const int bufoff = (t & 1) * BUFSZ;
        asm volatile("s_waitcnt lgkmcnt(0)" ::: "memory");   // done reading buf we overwrite
        __builtin_amdgcn_s_barrier();                        // B1
        if (t < 63) {
            STAGE((t + 1) * 128, BUFSZ - bufoff);
            asm volatile("s_waitcnt vmcnt(16)" ::: "memory"); // tile t landed; t+1 in flight
        } else {
            asm volatile("s_waitcnt vmcnt(0)" ::: "memory");
        }
        __builtin_amdgcn_s_barrier();                        // B2

        const float ev = *reinterpret_cast<const float*>(e2p + t * 512);
        const char* bb = smem + bufoff + rloc * 512;

        f16v a0{}, a1{};
        #pragma unroll
        for (int ks = 0; ks < 16; ++ks) {
            const s8v bf = *reinterpret_cast<const s8v*>(bb + ((ks * 32 + hi * 16) ^ sx));
            a0 = __builtin_amdgcn_mfma_f32_32x32x16_bf16(afr[0][ks], bf, a0, 0, 0, 0);
            a1 = __builtin_amdgcn_mfma_f32_32x32x16_bf16(afr[1][ks], bf, a1, 0, 0, 0);
        }

        const int cbw = t * 128 + w * 32;
        #pragma unroll
        for (int r = 0; r < 16; ++r) {
            const float s0 = fmaf(-2.0f, a0[r], ev);
            if (s0 < minv0[r]) { minv0[r] = s0; minc0[r] = cbw; }
            const float s1 = fmaf(-2.0f, a1[r], ev);
            if (s1 < minv1[r]) { minv1[r] = s1; minc1[r] = cbw; }
        }
    }

    // ---- final reduce: butterfly over 32 col-lanes, then cross-wave via LDS ----
    float* scrV = (float*)smem;              // buf0 region reused (safe post-loop)
    int*   scrC = (int*)(smem + 4096);
    #pragma unroll
    for (int mr = 0; mr < 2; ++mr)
        #pragma unroll
        for (int r = 0; r < 16; ++r) {
            float v = mr ? minv1[r] : minv0[r];
            int   c = (mr ? minc1[r] : minc0[r]) + l31;
            #pragma unroll
            for (int m = 1; m <= 16; m <<= 1) {
                const float v2 = __shfl_xor(v, m, 64);
                const int   c2 = __shfl_xor(c, m, 64);
                if (v2 < v || (v2 == v && c2 < c)) { v = v2; c = c2; }
            }
            if (l31 == 0) {
                const int row = mr * 32 + (r & 3) + 8 * (r >> 2) + 4 * hi;
                scrV[w * 64 + row] = v;
                scrC[w * 64 + row] = c;
            }
        }
    __syncthreads();
    if (tid < 64) {
        float v = scrV[tid]; int c = scrC[tid];
        #pragma unroll
        for (int ww = 1; ww < 4; ++ww) {
            const float v2 = scrV[ww * 64 + tid];
            const int   c2 = scrC[ww * 64 + tid];
            if (v2 < v || (v2 == v && c2 < c)) { v = v2; c = c2; }
        }
        idxout[row0 + tid] = c;
    }
}

// ---------- kernel 4: gather + straight-through output + loss partial ----------
__global__ void __launch_bounds__(256)
k_gather_loss(const float* __restrict__ x, const float* __restrict__ cb,
              const int* __restrict__ idx, float* __restrict__ out,
              float* __restrict__ loss) {
    __shared__ float q[32][257];
    __shared__ int e_s[32];
    const int tid = threadIdx.x;
    const int hw0 = (blockIdx.x & 31) * 32;
    const int b   = blockIdx.x >> 5;
    const int n0  = (b << 10) + hw0;
    if (tid < 32) e_s[tid] = idx[n0 + tid];
    __syncthreads();
    #pragma unroll 8
    for (int r = 0; r < 32; ++r)
        q[r][tid] = cb[(size_t)e_s[r] * EMBED_DIM + tid];
    __syncthreads();
    const int tx = tid & 31;    // hw offset within tile
    const int ty = tid >> 5;    // 0..7  (channel group)
    float sum = 0.f;
    #pragma unroll
    for (int i = 0; i < 32; ++i) {
        const int c = ty * 32 + i;
        const float qv = q[tx][c];
        const int o = ((b * EMBED_DIM + c) << 10) + hw0 + tx;
        const float xv = x[o];
        out[o] = qv;
        const float d = qv - xv;
        sum = fmaf(d, d, sum);
    }
    #pragma unroll
    for (int off = 32; off > 0; off >>= 1) sum += __shfl_down(sum, off, 64);
    __shared__ float ls[4];
    const int lane = tid & 63, wid = tid >> 6;
    if (lane == 0) ls[wid] = sum;
    __syncthreads();
    if (tid == 0) atomicAdd(loss, ls[0] + ls[1] + ls[2] + ls[3]);
}

// ---------- kernel 5: finalize loss ----------
__global__ void k_finalize(const float* __restrict__ loss, float* __restrict__ out) {
    out[OUT0_ELEMS] = loss[0] * (1.25f / (float)OUT0_ELEMS);
}

extern "C" void kernel_launch(void* const* d_in, const int* in_sizes, int n_in,
                              void* d_out, int out_size, void* d_ws, size_t ws_size,
                              hipStream_t stream) {
    const float* x  = (const float*)d_in[0];
    const float* cb = (const float*)d_in[1];
    float* out = (float*)d_out;

    char* ws = (char*)d_ws;
    unsigned short* xb = (unsigned short*)ws;                         // 8 MB
    unsigned short* eb = (unsigned short*)(ws + 8388608);             // 4 MB
    float* e2   = (float*)(ws + 12582912);                            // 32 KB
    int*   idx  = (int*)(ws + 12615680);                              // 64 KB
    float* loss = (float*)(ws + 12681216);                            // 4 B

    k_transpose_x<<<dim3(32, 8, 16), dim3(32, 8, 1), 0, stream>>>(x, xb, loss);
    k_convert_cb<<<dim3(NUM_EMBEDS), dim3(256), 0, stream>>>(cb, eb, e2);
    k_argmin<<<dim3(NVEC / 64), dim3(256), SMEMSZ, stream>>>(xb, eb, e2, idx);
    k_gather_loss<<<dim3(512), dim3(256), 0, stream>>>(x, cb, idx, out, loss);
    k_finalize<<<dim3(1), dim3(1), 0, stream>>>(loss, out);
}

// Round 5
// 106.749 us; speedup vs baseline: 2.7658x; 1.3388x over previous
//
#include <hip/hip_runtime.h>
#include <hip/hip_bf16.h>

// ---------- types ----------
typedef short s8v  __attribute__((ext_vector_type(8)));   // 8 x bf16 (4 VGPRs)
typedef float f16v __attribute__((ext_vector_type(16)));  // 32x32 accumulator

#define NUM_EMBEDS 8192
#define EMBED_DIM  256
#define BATCH      16
#define HW         1024
#define NVEC       (BATCH * HW)              // 16384
#define OUT0_ELEMS (BATCH * EMBED_DIM * HW)  // 4194304
#define NSPLIT     4                         // column splits
#define COLS_PER_S 2048                      // 8192 / NSPLIT
#define NTILES     64                        // COLS_PER_S / 32

// k_argmin LDS map (dynamic, 40 KiB):
//   buf0 @ 0      (16 KiB) B tile [32 cols][512B], XOR-swizzled 16B chunks
//   buf1 @ 16384  (16 KiB)
//   e2   @ 32768  (8 KiB)  this block's 2048 e2 floats
#define BUFB  16384
#define E2L   32768
#define SMEM3 40960

static __device__ __forceinline__ unsigned short f32_to_bf16_rne(float f) {
    unsigned int u = __float_as_uint(f);
    unsigned int r = u + 0x7FFFu + ((u >> 16) & 1u);
    return (unsigned short)(r >> 16);
}

static __device__ __forceinline__ void gload_lds16(const void* g, void* l) {
    __builtin_amdgcn_global_load_lds(
        (const __attribute__((address_space(1))) unsigned int*)g,
        (__attribute__((address_space(3))) unsigned int*)l, 16, 0, 0);
}

// ---------- kernel 1: transpose x [16][256][1024] f32 -> xb [16384][256] bf16 ----------
__global__ void k_transpose_x(const float* __restrict__ x, unsigned short* __restrict__ xb,
                              float* __restrict__ loss) {
    __shared__ float t[32][33];
    const int tx = threadIdx.x;          // 0..31
    const int ty = threadIdx.y;          // 0..7
    const int hw0 = blockIdx.x * 32;
    const int c0  = blockIdx.y * 32;
    const int b   = blockIdx.z;
    if (blockIdx.x == 0 && blockIdx.y == 0 && blockIdx.z == 0 && tx == 0 && ty == 0)
        *loss = 0.0f;
    #pragma unroll
    for (int i = 0; i < 4; ++i) {
        const int c = c0 + ty + i * 8;
        t[ty + i * 8][tx] = x[((b * EMBED_DIM + c) << 10) + hw0 + tx];
    }
    __syncthreads();
    #pragma unroll
    for (int i = 0; i < 4; ++i) {
        const int hw = hw0 + ty + i * 8;
        const int n = b * HW + hw;
        xb[n * EMBED_DIM + c0 + tx] = f32_to_bf16_rne(t[tx][ty + i * 8]);
    }
}

// ---------- kernel 2: codebook f32 -> bf16 + e2 ----------
__global__ void k_convert_cb(const float* __restrict__ cb, unsigned short* __restrict__ eb,
                             float* __restrict__ e2) {
    const int e = blockIdx.x;
    const int tid = threadIdx.x;      // 0..255
    const float v = cb[e * EMBED_DIM + tid];
    eb[e * EMBED_DIM + tid] = f32_to_bf16_rne(v);
    float s = v * v;
    #pragma unroll
    for (int off = 32; off > 0; off >>= 1) s += __shfl_down(s, off, 64);
    __shared__ float ls[4];
    const int lane = tid & 63, wid = tid >> 6;
    if (lane == 0) ls[wid] = s;
    __syncthreads();
    if (tid == 0) e2[e] = ls[0] + ls[1] + ls[2] + ls[3];
}

// ---------- kernel 3: fused GEMM + argmin ----------
// Grid 256 = 64 row-blocks x 4 col-splits; s = blockIdx.x & 3 so each XCD
// (blk%8 round-robin) serves one 1MB codebook col-slice -> L2-resident.
// Block: 512 thr = 8 waves; BM=256 rows (32/wave, A in 64 VGPR); tile = 32 cols.
__global__ void __launch_bounds__(512, 2)
k_argmin(const unsigned short* __restrict__ xb, const unsigned short* __restrict__ eb,
         const float* __restrict__ e2, float* __restrict__ pv, int* __restrict__ pi) {
    extern __shared__ char smem[];
    const int tid  = threadIdx.x;
    const int lane = tid & 63;
    const int w    = tid >> 6;           // wave 0..7
    const int l31  = lane & 31;
    const int hi   = lane >> 5;          // 0/1
    const int s    = blockIdx.x & 3;
    const int rb   = blockIdx.x >> 2;
    const int row0 = rb * 256;
    const int cb0  = s * COLS_PER_S;

    const char* xbB = (const char*)xb;
    const char* ebB = (const char*)eb;
    const char* e2B = (const char*)e2;

    // ---- A fragments straight from global: 32 rows/wave, 16 s8v = 64 VGPR ----
    // 32x32x16 A layout: lane row = l31, k = ks*16 + hi*8 + j
    s8v afr[16];
    const int arow = row0 + w * 32 + l31;
    #pragma unroll
    for (int ks = 0; ks < 16; ++ks)
        afr[ks] = *reinterpret_cast<const s8v*>(
            xbB + ((size_t)arow << 9) + ks * 32 + hi * 16);

    // ---- e2 slice stage: 8 KiB, 1 instr/wave ----
    gload_lds16(e2B + ((size_t)cb0 << 2) + w * 1024 + lane * 16, smem + E2L + w * 1024);

    // ---- B staging: [32 cols][512B] row-major, chunk-XOR swizzle, coalesced src ----
    // instr (w,j): p = w*2+j, rows 2p,2p+1 via hi; 1KB contiguous LDS dest.
    // LDS chunk c of row r holds global chunk c^(r&7).
    auto STAGE = [&](int tci, int lds_off) {
        #pragma unroll
        for (int j = 0; j < 2; ++j) {
            const int p = w * 2 + j;
            const int r = 2 * p + hi;
            gload_lds16(ebB + ((size_t)(cb0 + tci * 32 + r) << 9) + ((l31 ^ (r & 7)) << 4),
                        smem + lds_off + p * 1024);
        }
    };
    STAGE(0, 0);

    // pin A in registers (no sinking/rematerialization)
    #pragma unroll
    for (int ks = 0; ks < 16; ++ks)
        asm volatile("" : "+v"(afr[ks]));

    asm volatile("s_waitcnt vmcnt(0) lgkmcnt(0)" ::: "memory");
    __builtin_amdgcn_s_barrier();
    asm volatile("" ::: "memory");

    float minv[16];
    int   minc[16];
    #pragma unroll
    for (int r = 0; r < 16; ++r) { minv[r] = 3.4e38f; minc[r] = 0; }

    const int sx = (l31 & 7) << 4;       // read-side swizzle (B col = l31)

    for (int t = 0; t < NTILES; ++t) {
        const int bufoff = (t & 1) * BUFB;
        if (t < NTILES - 1) {
            STAGE(t + 1, BUFB - bufoff);
            asm volatile("s_waitcnt vmcnt(2)" ::: "memory");  // tile t landed; t+1 in flight
        } else {
            asm volatile("s_waitcnt vmcnt(0)" ::: "memory");
        }
        __builtin_amdgcn_s_barrier();                         // staged tile visible to all
        asm volatile("" ::: "memory");

        const float ev = *reinterpret_cast<const float*>(smem + E2L + t * 128 + l31 * 4);
        const char* bb = smem + bufoff + l31 * 512;

        f16v acc{};
        #pragma unroll
        for (int ks = 0; ks < 16; ++ks) {
            const s8v bf = *reinterpret_cast<const s8v*>(bb + ((ks * 32 + hi * 16) ^ sx));
            acc = __builtin_amdgcn_mfma_f32_32x32x16_bf16(afr[ks], bf, acc, 0, 0, 0);
        }

        const int colr = cb0 + t * 32 + l31;
        #pragma unroll
        for (int r = 0; r < 16; ++r) {
            const float sc = fmaf(-2.0f, acc[r], ev);
            if (sc < minv[r]) { minv[r] = sc; minc[r] = colr; }
        }

        asm volatile("s_waitcnt lgkmcnt(0)" ::: "memory");    // reads done before overwrite
        __builtin_amdgcn_s_barrier();
        asm volatile("" ::: "memory");
    }

    // ---- reduce over 32 col-lanes (butterfly); rows are disjoint across waves/hi ----
    #pragma unroll
    for (int r = 0; r < 16; ++r) {
        float v = minv[r]; int c = minc[r];
        #pragma unroll
        for (int m = 1; m <= 16; m <<= 1) {
            const float v2 = __shfl_xor(v, m, 64);
            const int   c2 = __shfl_xor(c, m, 64);
            if (v2 < v || (v2 == v && c2 < c)) { v = v2; c = c2; }
        }
        if (l31 == 0) {
            const int row_g = row0 + w * 32 + (r & 3) + 8 * (r >> 2) + 4 * hi;
            pv[s * NVEC + row_g] = v;
            pi[s * NVEC + row_g] = c;
        }
    }
}

// ---------- kernel 3b: merge column-split partials ----------
__global__ void k_merge(const float* __restrict__ pv, const int* __restrict__ pi,
                        int* __restrict__ idxout) {
    const int row = blockIdx.x * 256 + threadIdx.x;
    float v = pv[row]; int i = pi[row];
    #pragma unroll
    for (int s = 1; s < NSPLIT; ++s) {
        const float v2 = pv[s * NVEC + row];
        const int   i2 = pi[s * NVEC + row];
        if (v2 < v || (v2 == v && i2 < i)) { v = v2; i = i2; }
    }
    idxout[row] = i;
}

// ---------- kernel 4: gather + straight-through output + loss partial ----------
__global__ void __launch_bounds__(256)
k_gather_loss(const float* __restrict__ x, const float* __restrict__ cb,
              const int* __restrict__ idx, float* __restrict__ out,
              float* __restrict__ loss) {
    __shared__ float q[32][257];
    __shared__ int e_s[32];
    const int tid = threadIdx.x;
    const int hw0 = (blockIdx.x & 31) * 32;
    const int b   = blockIdx.x >> 5;
    const int n0  = (b << 10) + hw0;
    if (tid < 32) e_s[tid] = idx[n0 + tid];
    __syncthreads();
    #pragma unroll 8
    for (int r = 0; r < 32; ++r)
        q[r][tid] = cb[(size_t)e_s[r] * EMBED_DIM + tid];
    __syncthreads();
    const int tx = tid & 31;    // hw offset within tile
    const int ty = tid >> 5;    // 0..7  (channel group)
    float sum = 0.f;
    #pragma unroll
    for (int i = 0; i < 32; ++i) {
        const int c = ty * 32 + i;
        const float qv = q[tx][c];
        const int o = ((b * EMBED_DIM + c) << 10) + hw0 + tx;
        const float xv = x[o];
        out[o] = qv;
        const float d = qv - xv;
        sum = fmaf(d, d, sum);
    }
    #pragma unroll
    for (int off = 32; off > 0; off >>= 1) sum += __shfl_down(sum, off, 64);
    __shared__ float ls[4];
    const int lane = tid & 63, wid = tid >> 6;
    if (lane == 0) ls[wid] = sum;
    __syncthreads();
    if (tid == 0) atomicAdd(loss, ls[0] + ls[1] + ls[2] + ls[3]);
}

// ---------- kernel 5: finalize loss ----------
__global__ void k_finalize(const float* __restrict__ loss, float* __restrict__ out) {
    out[OUT0_ELEMS] = loss[0] * (1.25f / (float)OUT0_ELEMS);
}

extern "C" void kernel_launch(void* const* d_in, const int* in_sizes, int n_in,
                              void* d_out, int out_size, void* d_ws, size_t ws_size,
                              hipStream_t stream) {
    const float* x  = (const float*)d_in[0];
    const float* cb = (const float*)d_in[1];
    float* out = (float*)d_out;

    char* ws = (char*)d_ws;
    unsigned short* xb = (unsigned short*)ws;                         // 8 MB
    unsigned short* eb = (unsigned short*)(ws + 8388608);             // 4 MB
    float* e2   = (float*)(ws + 12582912);                            // 32 KB
    int*   idx  = (int*)(ws + 12615680);                              // 64 KB
    float* loss = (float*)(ws + 12681216);                            // 4 B (pad 512)
    float* pv   = (float*)(ws + 12681728);                            // 256 KB
    int*   pi   = (int*)(ws + 12943872);                              // 256 KB

    k_transpose_x<<<dim3(32, 8, 16), dim3(32, 8, 1), 0, stream>>>(x, xb, loss);
    k_convert_cb<<<dim3(NUM_EMBEDS), dim3(256), 0, stream>>>(cb, eb, e2);
    k_argmin<<<dim3(64 * NSPLIT), dim3(512), SMEM3, stream>>>(xb, eb, e2, pv, pi);
    k_merge<<<dim3(NVEC / 256), dim3(256), 0, stream>>>(pv, pi, idx);
    k_gather_loss<<<dim3(512), dim3(256), 0, stream>>>(x, cb, idx, out, loss);
    k_finalize<<<dim3(1), dim3(1), 0, stream>>>(loss, out);
}